// Round 1
// baseline (70.170 us; speedup 1.0000x reference)
//
#include <hip/hip_runtime.h>

// ConvCNP: out[b,m,o] = b[o] + sum_c W[o,c] * y_out[b,m,c]
//   y_out[...,0]   = density = sum_n exp(-0.5 (x[b,n]-t[b,m])^2 / s_0^2)
//   y_out[...,c>0] = (sum_n y[b,n,c-1] * exp(-0.5 d / s_c^2)) / (density + 1e-8)
// Shapes: B=8, N=M=1024, C_IN=8, C_REP=9, C_OUT=16. All fp32.

#define B_    8
#define N_    1024
#define M_    1024
#define CIN   8
#define COUT  16
#define CREP  9
#define MTILE 16      // m-values per block
#define NGRP  16      // n-groups per block (threads = MTILE*NGRP = 256)
#define KITER (N_ / NGRP)   // 64 n-iterations per thread

#if __has_builtin(__builtin_amdgcn_exp2f)
#define EXP2F(v) __builtin_amdgcn_exp2f(v)
#else
#define EXP2F(v) exp2f(v)
#endif

__global__ __launch_bounds__(256) void convcnp_kernel(
    const float* __restrict__ x,      // [B,N]
    const float* __restrict__ y,      // [B,N,CIN]
    const float* __restrict__ t,      // [B,M]
    const float* __restrict__ sigma,  // [CREP]
    const float* __restrict__ W,      // [COUT,CREP]
    const float* __restrict__ bias,   // [COUT]
    float* __restrict__ out)          // [B,M,COUT]
{
    __shared__ float x_lds[N_];
    __shared__ float y_lds[N_ * CIN];
    __shared__ float red[4][MTILE][CREP];
    __shared__ float fin[MTILE][CREP];

    const int tid  = threadIdx.x;
    const int bb   = blockIdx.x >> 6;     // 64 m-tiles per batch
    const int tile = blockIdx.x & 63;
    const int m0   = tile * MTILE;

    // ---- stage x (4KB) and y (32KB) into LDS, float4 coalesced ----
    const float4* x4  = (const float4*)(x + bb * N_);
    float4*       xl4 = (float4*)x_lds;
    xl4[tid] = x4[tid];
    const float4* y4  = (const float4*)(y + bb * N_ * CIN);
    float4*       yl4 = (float4*)y_lds;
#pragma unroll
    for (int j = 0; j < 8; ++j) yl4[tid + j * 256] = y4[tid + j * 256];

    // ---- per-channel exponent constants: k_c = -0.5/ s_c^2 * log2(e) ----
    // s_c = exp(sigma_c)  =>  1/s_c^2 = exp(-2 sigma_c) = 2^(-2 sigma_c log2 e)
    float kc[CREP];
#pragma unroll
    for (int c = 0; c < CREP; ++c)
        kc[c] = -0.72134752044f * EXP2F(-2.88539008178f * sigma[c]);
    bool uni = true;
#pragma unroll
    for (int c = 1; c < CREP; ++c) uni = uni && (kc[c] == kc[0]);

    const int   m_loc = tid & 15;
    const int   g     = tid >> 4;          // n-group 0..15
    const float tv    = t[bb * M_ + m0 + m_loc];

    float acc[CREP];
#pragma unroll
    for (int c = 0; c < CREP; ++c) acc[c] = 0.f;

    __syncthreads();

    if (uni) {
        // uniform scales: one exp serves all 9 channels
        const float k0 = kc[0];
#pragma unroll 4
        for (int k = 0; k < KITER; ++k) {
            const int    n  = g + (k << 4);
            const float  xv = x_lds[n];
            const float4 ya = *(const float4*)(y_lds + n * CIN);
            const float4 yb = *(const float4*)(y_lds + n * CIN + 4);
            float d = xv - tv; d *= d;
            const float w = EXP2F(k0 * d);
            acc[0] += w;
            acc[1] += ya.x * w; acc[2] += ya.y * w;
            acc[3] += ya.z * w; acc[4] += ya.w * w;
            acc[5] += yb.x * w; acc[6] += yb.y * w;
            acc[7] += yb.z * w; acc[8] += yb.w * w;
        }
    } else {
        // general per-channel scales: 9 exps per pair
#pragma unroll 2
        for (int k = 0; k < KITER; ++k) {
            const int    n  = g + (k << 4);
            const float  xv = x_lds[n];
            const float4 ya = *(const float4*)(y_lds + n * CIN);
            const float4 yb = *(const float4*)(y_lds + n * CIN + 4);
            float d = xv - tv; d *= d;
            const float yr[CREP] = {1.f, ya.x, ya.y, ya.z, ya.w,
                                         yb.x, yb.y, yb.z, yb.w};
#pragma unroll
            for (int c = 0; c < CREP; ++c)
                acc[c] += yr[c] * EXP2F(kc[c] * d);
        }
    }

    // ---- reduce 4 groups within each wave (lanes l, l^16, l^32, l^48) ----
#pragma unroll
    for (int c = 0; c < CREP; ++c) {
        acc[c] += __shfl_xor(acc[c], 16, 64);
        acc[c] += __shfl_xor(acc[c], 32, 64);
    }
    const int w_id = tid >> 6;
    const int lane = tid & 63;
    if (lane < MTILE) {
#pragma unroll
        for (int c = 0; c < CREP; ++c) red[w_id][lane][c] = acc[c];
    }
    __syncthreads();

    // ---- reduce 4 waves ----
    for (int idx = tid; idx < MTILE * CREP; idx += 256) {
        const int m = idx / CREP, c = idx - m * CREP;
        fin[m][c] = red[0][m][c] + red[1][m][c] + red[2][m][c] + red[3][m][c];
    }
    __syncthreads();

    // ---- epilogue: one (m, o) output per thread ----
    const int o = tid & 15;
    const int m = tid >> 4;
    const float dens = fin[m][0];
    const float inv  = 1.0f / (dens + 1e-8f);
    float r = bias[o] + W[o * CREP] * dens;
#pragma unroll
    for (int c = 1; c < CREP; ++c) r += W[o * CREP + c] * (fin[m][c] * inv);
    out[(bb * M_ + m0 + m) * COUT + o] = r;
}

extern "C" void kernel_launch(void* const* d_in, const int* in_sizes, int n_in,
                              void* d_out, int out_size, void* d_ws, size_t ws_size,
                              hipStream_t stream) {
    const float* x     = (const float*)d_in[0];
    const float* y     = (const float*)d_in[1];
    const float* t     = (const float*)d_in[2];
    const float* sigma = (const float*)d_in[3];
    const float* W     = (const float*)d_in[4];
    const float* bias  = (const float*)d_in[5];
    float*       out   = (float*)d_out;

    convcnp_kernel<<<dim3(B_ * (M_ / MTILE)), dim3(256), 0, stream>>>(
        x, y, t, sigma, W, bias, out);
}